// Round 7
// baseline (174.576 us; speedup 1.0000x reference)
//
#include <hip/hip_runtime.h>

// Linear attention, fp32. N=8, L=S=8192, H=8, D=Dv=32.
// out[n,l,h,v] = (sum_d phiQ[l,d]*KV[d][v]) * 1/(sum_d phiQ[l,d]*Ksum[d] + 1e-6)
// where KV[d][v] = sum_s phiK[s,d]*values[s,v]  (the /S and *S of the reference
// cancel exactly: S is a power of two).
//
// R7: BOTH phases rebuilt LDS-free. R5's rocprof exposed phase1 at ~62us too
// (512 ds-ops x 9cyc x 32 waves/CU = 61us -> LDS-pipe bound), and phase2's
// variants were all LDS/latency bound at <=2 waves/SIMD. Now the hot loops
// read K/V/Q/KV directly from global (wave-level broadcast patterns merge in
// L1/L2), registers hold all accumulators, occupancy ~4-5 waves/SIMD.

#define N_      8
#define L_      8192
#define S_      8192
#define H_      8
#define D_      32
#define NH_     64            // N*H
#define CH_     16            // phase-1 s-chunks per (n,h)
#define SPC_    (S_ / CH_)    // 512 s per block
#define SPW_    (SPC_ / 4)    // 128 s per wave
#define KVE_    (D_ * D_)     // 1024
#define PKS_    (KVE_ + D_)   // 1056 floats: KV + Ksum
#define RPB_    32            // phase2: (n,l)-rows per block

__device__ __forceinline__ float phi_f(float x) {
    // elu(x)+1 : x>0 -> x+1 ; else exp(x)
    return x > 0.f ? x + 1.f : __expf(x);
}

// ---------------- Phase 1: KV + Ksum accumulation over s (LDS-free loop) ----
// Lane: dp = lane&15 -> d in {2dp, 2dp+1}; vg = lane>>4 -> v in [8vg, 8vg+8).
// Wave pattern per s: K float2 (16 lanes cover 128B coalesced, 4x broadcast),
// V 2x float4 (4 distinct 16B, 16-lane broadcast each) -> L1 merges all.
template <bool ATOMIC>
__global__ __launch_bounds__(256, 4) void la_phase1(
    const float* __restrict__ keys, const float* __restrict__ values,
    float* __restrict__ outp /* ATOMIC ? kvfinal[NH][PKS] : partials[NH][CH][PKS] */)
{
    __shared__ float red[4][PKS_];   // per-wave partials (cold, 16.9 KB)
    const int nh    = blockIdx.x;    // 0..63
    const int chunk = blockIdx.y;    // 0..15
    const int n = nh >> 3, h = nh & 7;
    const int t = threadIdx.x, lane = t & 63, w = t >> 6;
    const int dp = lane & 15;        // d0 = 2*dp
    const int vg = lane >> 4;        // v0 = 8*vg
    const int d0 = dp << 1, v0 = vg << 3;

    const float* kp = keys   + (size_t)(n * S_ + chunk * SPC_ + w * SPW_) * 256 + h * D_ + d0;
    const float* vp = values + (size_t)(n * S_ + chunk * SPC_ + w * SPW_) * 256 + h * D_ + v0;

    float acc0[8], acc1[8];
    float ks0 = 0.f, ks1 = 0.f;
#pragma unroll
    for (int j = 0; j < 8; ++j) { acc0[j] = 0.f; acc1[j] = 0.f; }

#pragma unroll 4
    for (int s = 0; s < SPW_; ++s) {
        const float2 k2 = *(const float2*)(kp + (size_t)s * 256);
        const float4 va = *(const float4*)(vp + (size_t)s * 256);
        const float4 vc = *(const float4*)(vp + (size_t)s * 256 + 4);
        const float p0 = phi_f(k2.x), p1 = phi_f(k2.y);
        ks0 += p0; ks1 += p1;
        const float vv[8] = {va.x, va.y, va.z, va.w, vc.x, vc.y, vc.z, vc.w};
#pragma unroll
        for (int j = 0; j < 8; ++j) {
            acc0[j] = fmaf(p0, vv[j], acc0[j]);
            acc1[j] = fmaf(p1, vv[j], acc1[j]);
        }
    }

    // per-wave partial -> LDS (cold path)
#pragma unroll
    for (int j = 0; j < 8; ++j) red[w][(d0 + 0) * D_ + v0 + j] = acc0[j];
#pragma unroll
    for (int j = 0; j < 8; ++j) red[w][(d0 + 1) * D_ + v0 + j] = acc1[j];
    if (vg == 0) { red[w][KVE_ + d0] = ks0; red[w][KVE_ + d0 + 1] = ks1; }
    __syncthreads();

    // deterministic 4-wave combine, then chunk-partial out
    for (int e = t; e < PKS_; e += 256) {
        const float ssum = (red[0][e] + red[1][e]) + (red[2][e] + red[3][e]);
        if (ATOMIC) atomicAdd(&outp[(size_t)nh * PKS_ + e], ssum);
        else        outp[((size_t)nh * CH_ + chunk) * PKS_ + e] = ssum;
    }
}

// ---------------- Phase 1b: deterministic 16-way partial reduce ----------------
__global__ __launch_bounds__(256) void la_reduce(
    const float* __restrict__ partials, float* __restrict__ kvf)
{
    const int nh = blockIdx.x;
    for (int e = threadIdx.x; e < PKS_; e += 256) {
        const float* p = partials + (size_t)nh * CH_ * PKS_ + e;
        float s = 0.f;
#pragma unroll
        for (int c = 0; c < CH_; ++c) s += p[(size_t)c * PKS_];
        kvf[(size_t)nh * PKS_ + e] = s;
    }
}

__global__ void la_zero(float* __restrict__ p, int nelem) {
    const int i = blockIdx.x * 256 + threadIdx.x;
    if (i < nelem) p[i] = 0.f;
}

// ---------------- Phase 2: out = (phiQ . KV) * z (fully LDS-free) ----------
// Block = 32 consecutive (n,l) rows x ALL 8 heads; wave w owns rows 8w..8w+7.
// Lane: h = lane>>3, vs = lane&7. Per d-chunk (8 d's) the thread's KV slice
// (8 float4) comes straight from L2-hot kvf; Q read from global (vs-lane
// broadcast merges in L1); phi recomputed per use. 1KB dense wave-stores.
__global__ __launch_bounds__(256, 4) void la_phase2(
    const float* __restrict__ queries, const float* __restrict__ kvf,
    float* __restrict__ out)
{
    const int t = threadIdx.x, lane = t & 63, w = t >> 6;
    const int h = lane >> 3, vs = lane & 7;
    const size_t rowg0 = (size_t)blockIdx.x * RPB_;   // global (n,l)-row base
    const int n = (int)(rowg0 >> 13);                 // rowg0 / L_
    const float* kvb = kvf + (size_t)(n * 8 + h) * PKS_;
    const float4* qg = (const float4*)(queries + rowg0 * 256);
    float4* og = (float4*)(out + rowg0 * 256);
    const int r0 = w << 3;

    float acc[8][4], dot[8];
#pragma unroll
    for (int r = 0; r < 8; ++r) {
        dot[r] = 0.f;
#pragma unroll
        for (int j = 0; j < 4; ++j) acc[r][j] = 0.f;
    }

#pragma unroll
    for (int c = 0; c < 4; ++c) {                 // d-chunk: d in [8c, 8c+8)
        float4 kvc[8];                            // thread's KV slice: 32 regs
#pragma unroll
        for (int j = 0; j < 8; ++j)
            kvc[j] = *(const float4*)(kvb + ((c << 3) + j) * D_ + (vs << 2));
        const float4 ksA = *(const float4*)(kvb + KVE_ + (c << 3));
        const float4 ksB = *(const float4*)(kvb + KVE_ + (c << 3) + 4);

#pragma unroll
        for (int r = 0; r < 8; ++r) {
            float4 q0 = qg[(size_t)(r0 + r) * 64 + (h << 3) + (c << 1)];
            float4 q1 = qg[(size_t)(r0 + r) * 64 + (h << 3) + (c << 1) + 1];
            q0 = make_float4(phi_f(q0.x), phi_f(q0.y), phi_f(q0.z), phi_f(q0.w));
            q1 = make_float4(phi_f(q1.x), phi_f(q1.y), phi_f(q1.z), phi_f(q1.w));
            float dt = dot[r];
            dt = fmaf(q0.x, ksA.x, dt); dt = fmaf(q0.y, ksA.y, dt);
            dt = fmaf(q0.z, ksA.z, dt); dt = fmaf(q0.w, ksA.w, dt);
            dt = fmaf(q1.x, ksB.x, dt); dt = fmaf(q1.y, ksB.y, dt);
            dt = fmaf(q1.z, ksB.z, dt); dt = fmaf(q1.w, ksB.w, dt);
            dot[r] = dt;
            float a0 = acc[r][0], a1 = acc[r][1], a2 = acc[r][2], a3 = acc[r][3];
            a0 = fmaf(q0.x, kvc[0].x, a0); a1 = fmaf(q0.x, kvc[0].y, a1);
            a2 = fmaf(q0.x, kvc[0].z, a2); a3 = fmaf(q0.x, kvc[0].w, a3);
            a0 = fmaf(q0.y, kvc[1].x, a0); a1 = fmaf(q0.y, kvc[1].y, a1);
            a2 = fmaf(q0.y, kvc[1].z, a2); a3 = fmaf(q0.y, kvc[1].w, a3);
            a0 = fmaf(q0.z, kvc[2].x, a0); a1 = fmaf(q0.z, kvc[2].y, a1);
            a2 = fmaf(q0.z, kvc[2].z, a2); a3 = fmaf(q0.z, kvc[2].w, a3);
            a0 = fmaf(q0.w, kvc[3].x, a0); a1 = fmaf(q0.w, kvc[3].y, a1);
            a2 = fmaf(q0.w, kvc[3].z, a2); a3 = fmaf(q0.w, kvc[3].w, a3);
            a0 = fmaf(q1.x, kvc[4].x, a0); a1 = fmaf(q1.x, kvc[4].y, a1);
            a2 = fmaf(q1.x, kvc[4].z, a2); a3 = fmaf(q1.x, kvc[4].w, a3);
            a0 = fmaf(q1.y, kvc[5].x, a0); a1 = fmaf(q1.y, kvc[5].y, a1);
            a2 = fmaf(q1.y, kvc[5].z, a2); a3 = fmaf(q1.y, kvc[5].w, a3);
            a0 = fmaf(q1.z, kvc[6].x, a0); a1 = fmaf(q1.z, kvc[6].y, a1);
            a2 = fmaf(q1.z, kvc[6].z, a2); a3 = fmaf(q1.z, kvc[6].w, a3);
            a0 = fmaf(q1.w, kvc[7].x, a0); a1 = fmaf(q1.w, kvc[7].y, a1);
            a2 = fmaf(q1.w, kvc[7].z, a2); a3 = fmaf(q1.w, kvc[7].w, a3);
            acc[r][0] = a0; acc[r][1] = a1; acc[r][2] = a2; acc[r][3] = a3;
        }
    }

#pragma unroll
    for (int r = 0; r < 8; ++r) {
        const float z = 1.f / (dot[r] + 1e-6f);
        // lanes 0..63 cover float4 0..63 of the row -> 1KB dense store
        og[(size_t)(r0 + r) * 64 + lane] =
            make_float4(acc[r][0] * z, acc[r][1] * z, acc[r][2] * z, acc[r][3] * z);
    }
}

extern "C" void kernel_launch(void* const* d_in, const int* in_sizes, int n_in,
                              void* d_out, int out_size, void* d_ws, size_t ws_size,
                              hipStream_t stream)
{
    const float* queries = (const float*)d_in[0];
    const float* keys    = (const float*)d_in[1];
    const float* values  = (const float*)d_in[2];
    float* out = (float*)d_out;
    float* ws  = (float*)d_ws;

    const size_t partial_elems = (size_t)NH_ * CH_ * PKS_;   // 1,081,344 floats
    const size_t final_elems   = (size_t)NH_ * PKS_;         // 67,584 floats
    const dim3 blk(256);
    const int p2_blocks = (N_ * L_) / RPB_;                  // 2048

    if (ws_size >= (partial_elems + final_elems) * sizeof(float)) {
        // deterministic two-stage reduction
        float* partials = ws;
        float* kvf      = ws + partial_elems;
        la_phase1<false><<<dim3(NH_, CH_), blk, 0, stream>>>(keys, values, partials);
        la_reduce<<<dim3(NH_), blk, 0, stream>>>(partials, kvf);
        la_phase2<<<dim3(p2_blocks), blk, 0, stream>>>(queries, kvf, out);
    } else {
        // fallback: atomic accumulation into zeroed final buffer
        float* kvf = ws;
        const int nz = (int)final_elems;
        la_zero<<<dim3((nz + 255) / 256), blk, 0, stream>>>(kvf, nz);
        la_phase1<true><<<dim3(NH_, CH_), blk, 0, stream>>>(keys, values, kvf);
        la_phase2<<<dim3(p2_blocks), blk, 0, stream>>>(queries, kvf, out);
    }
}

// Round 8
// 96.836 us; speedup vs baseline: 1.8028x; 1.8028x over previous
//
#include <hip/hip_runtime.h>

// Linear attention, fp32. N=8, L=S=8192, H=8, D=Dv=32.
// out[n,l,h,v] = (sum_d phiQ[l,d]*KV[d][v]) * 1/(sum_d phiQ[l,d]*Ksum[d] + 1e-6)
// where KV[d][v] = sum_s phiK[s,d]*values[s,v]  (the /S and *S of the reference
// cancel exactly: S is a power of two).
//
// R8: best-of-both. Phase1 = R1's LDS-staged version (timed ~18-21us incl.
// reduce; R7's LDS-free rebuild was 148us - strided 8B/lane starves DRAM).
// Phase2 = R7's LDS-free d-chunked version (inferred ~25-35us from R7's
// timed total; R5/R6 "dense-write tests" were invalidated by their own
// bank-conflict / occupancy bottlenecks).

#define N_      8
#define L_      8192
#define S_      8192
#define H_      8
#define D_      32
#define NH_     64            // N*H
#define CHUNKS_ 32            // phase-1 s-chunks per (n,h)
#define ROWS_   (S_ / CHUNKS_) // 256 rows per block
#define TILE_   64            // staged rows per LDS tile
#define KVE_    (D_ * D_)     // 1024
#define PKS_    (KVE_ + D_)   // 1056 floats: KV + Ksum
#define RPB_    32            // phase2: (n,l)-rows per block

__device__ __forceinline__ float phi_f(float x) {
    // elu(x)+1 : x>0 -> x+1 ; else exp(x)
    return x > 0.f ? x + 1.f : __expf(x);
}

// ---------------- Phase 1: KV + Ksum accumulation over s ----------------
template <bool ATOMIC>
__global__ __launch_bounds__(256) void la_phase1(
    const float* __restrict__ keys, const float* __restrict__ values,
    float* __restrict__ outp /* ATOMIC ? kvfinal[NH][PKS] : partials[NH][CHUNKS][PKS] */)
{
    __shared__ float kT[TILE_][D_];
    __shared__ float vT[TILE_][D_];
    const int nh    = blockIdx.x;   // 0..63
    const int chunk = blockIdx.y;   // 0..31
    const int n = nh >> 3, h = nh & 7;
    const int t  = threadIdx.x;
    const int d  = t & 31;          // this thread's K-dim
    const int vg = t >> 5;          // v-group: 4 consecutive v columns
    const size_t rs = (size_t)H_ * D_;   // 256 floats per (n,s) row
    const float* kbase = keys   + ((size_t)n * S_) * rs + (size_t)h * D_;
    const float* vbase = values + ((size_t)n * S_) * rs + (size_t)h * D_;
    const int s0 = chunk * ROWS_;

    float a0 = 0.f, a1 = 0.f, a2 = 0.f, a3 = 0.f, ksum = 0.f;

    for (int tb = 0; tb < ROWS_; tb += TILE_) {
        __syncthreads();
        // stage 64 rows of K (phi applied) and V; coalesced: 8 threads per row
#pragma unroll
        for (int i = 0; i < 2; ++i) {
            const int f   = t + i * 256;      // 0..511
            const int row = f >> 3;           // 0..63
            const int col = (f & 7) << 2;     // 0,4,...,28
            const size_t g = (size_t)(s0 + tb + row) * rs + col;
            const float4 k4 = *(const float4*)(kbase + g);
            const float4 v4 = *(const float4*)(vbase + g);
            *(float4*)&kT[row][col] =
                make_float4(phi_f(k4.x), phi_f(k4.y), phi_f(k4.z), phi_f(k4.w));
            *(float4*)&vT[row][col] = v4;
        }
        __syncthreads();
#pragma unroll 16
        for (int s = 0; s < TILE_; ++s) {
            const float  kk = kT[s][d];                        // b32, lanes->banks 0..31
            const float4 vv = *(const float4*)&vT[s][vg << 2]; // broadcast b128
            a0 = fmaf(kk, vv.x, a0);
            a1 = fmaf(kk, vv.y, a1);
            a2 = fmaf(kk, vv.z, a2);
            a3 = fmaf(kk, vv.w, a3);
            ksum += kk;   // identical across vg groups; only vg==0 stores it
        }
    }

    const int o = d * D_ + (vg << 2);
    if (ATOMIC) {
        float* p = outp + (size_t)nh * PKS_;
        atomicAdd(&p[o + 0], a0);
        atomicAdd(&p[o + 1], a1);
        atomicAdd(&p[o + 2], a2);
        atomicAdd(&p[o + 3], a3);
        if (vg == 0) atomicAdd(&p[KVE_ + d], ksum);
    } else {
        float* p = outp + ((size_t)nh * CHUNKS_ + chunk) * PKS_;
        *(float4*)&p[o] = make_float4(a0, a1, a2, a3);
        if (vg == 0) p[KVE_ + d] = ksum;
    }
}

// ---------------- Phase 1b: deterministic 32-way partial reduce ----------------
__global__ __launch_bounds__(256) void la_reduce(
    const float* __restrict__ partials, float* __restrict__ kvf)
{
    const int nh = blockIdx.x;
    for (int e = threadIdx.x; e < PKS_; e += 256) {
        const float* p = partials + (size_t)nh * CHUNKS_ * PKS_ + e;
        float s = 0.f;
#pragma unroll
        for (int c = 0; c < CHUNKS_; ++c) s += p[(size_t)c * PKS_];
        kvf[(size_t)nh * PKS_ + e] = s;
    }
}

__global__ void la_zero(float* __restrict__ p, int nelem) {
    const int i = blockIdx.x * 256 + threadIdx.x;
    if (i < nelem) p[i] = 0.f;
}

// ---------------- Phase 2: out = (phiQ . KV) * z (fully LDS-free) ----------
// Block = 32 consecutive (n,l) rows x ALL 8 heads; wave w owns rows 8w..8w+7.
// Lane: h = lane>>3, vs = lane&7. Per d-chunk (8 d's) the thread's KV slice
// (8 float4) comes straight from L2-hot kvf; Q read from global (vs-lane
// broadcast merges in L1); phi recomputed per use. 1KB dense wave-stores.
__global__ __launch_bounds__(256, 4) void la_phase2(
    const float* __restrict__ queries, const float* __restrict__ kvf,
    float* __restrict__ out)
{
    const int t = threadIdx.x, lane = t & 63, w = t >> 6;
    const int h = lane >> 3, vs = lane & 7;
    const size_t rowg0 = (size_t)blockIdx.x * RPB_;   // global (n,l)-row base
    const int n = (int)(rowg0 >> 13);                 // rowg0 / L_
    const float* kvb = kvf + (size_t)(n * 8 + h) * PKS_;
    const float4* qg = (const float4*)(queries + rowg0 * 256);
    float4* og = (float4*)(out + rowg0 * 256);
    const int r0 = w << 3;

    float acc[8][4], dot[8];
#pragma unroll
    for (int r = 0; r < 8; ++r) {
        dot[r] = 0.f;
#pragma unroll
        for (int j = 0; j < 4; ++j) acc[r][j] = 0.f;
    }

#pragma unroll
    for (int c = 0; c < 4; ++c) {                 // d-chunk: d in [8c, 8c+8)
        float4 kvc[8];                            // thread's KV slice: 32 regs
#pragma unroll
        for (int j = 0; j < 8; ++j)
            kvc[j] = *(const float4*)(kvb + ((c << 3) + j) * D_ + (vs << 2));
        const float4 ksA = *(const float4*)(kvb + KVE_ + (c << 3));
        const float4 ksB = *(const float4*)(kvb + KVE_ + (c << 3) + 4);

#pragma unroll
        for (int r = 0; r < 8; ++r) {
            float4 q0 = qg[(size_t)(r0 + r) * 64 + (h << 3) + (c << 1)];
            float4 q1 = qg[(size_t)(r0 + r) * 64 + (h << 3) + (c << 1) + 1];
            q0 = make_float4(phi_f(q0.x), phi_f(q0.y), phi_f(q0.z), phi_f(q0.w));
            q1 = make_float4(phi_f(q1.x), phi_f(q1.y), phi_f(q1.z), phi_f(q1.w));
            float dt = dot[r];
            dt = fmaf(q0.x, ksA.x, dt); dt = fmaf(q0.y, ksA.y, dt);
            dt = fmaf(q0.z, ksA.z, dt); dt = fmaf(q0.w, ksA.w, dt);
            dt = fmaf(q1.x, ksB.x, dt); dt = fmaf(q1.y, ksB.y, dt);
            dt = fmaf(q1.z, ksB.z, dt); dt = fmaf(q1.w, ksB.w, dt);
            dot[r] = dt;
            float a0 = acc[r][0], a1 = acc[r][1], a2 = acc[r][2], a3 = acc[r][3];
            a0 = fmaf(q0.x, kvc[0].x, a0); a1 = fmaf(q0.x, kvc[0].y, a1);
            a2 = fmaf(q0.x, kvc[0].z, a2); a3 = fmaf(q0.x, kvc[0].w, a3);
            a0 = fmaf(q0.y, kvc[1].x, a0); a1 = fmaf(q0.y, kvc[1].y, a1);
            a2 = fmaf(q0.y, kvc[1].z, a2); a3 = fmaf(q0.y, kvc[1].w, a3);
            a0 = fmaf(q0.z, kvc[2].x, a0); a1 = fmaf(q0.z, kvc[2].y, a1);
            a2 = fmaf(q0.z, kvc[2].z, a2); a3 = fmaf(q0.z, kvc[2].w, a3);
            a0 = fmaf(q0.w, kvc[3].x, a0); a1 = fmaf(q0.w, kvc[3].y, a1);
            a2 = fmaf(q0.w, kvc[3].z, a2); a3 = fmaf(q0.w, kvc[3].w, a3);
            a0 = fmaf(q1.x, kvc[4].x, a0); a1 = fmaf(q1.x, kvc[4].y, a1);
            a2 = fmaf(q1.x, kvc[4].z, a2); a3 = fmaf(q1.x, kvc[4].w, a3);
            a0 = fmaf(q1.y, kvc[5].x, a0); a1 = fmaf(q1.y, kvc[5].y, a1);
            a2 = fmaf(q1.y, kvc[5].z, a2); a3 = fmaf(q1.y, kvc[5].w, a3);
            a0 = fmaf(q1.z, kvc[6].x, a0); a1 = fmaf(q1.z, kvc[6].y, a1);
            a2 = fmaf(q1.z, kvc[6].z, a2); a3 = fmaf(q1.z, kvc[6].w, a3);
            a0 = fmaf(q1.w, kvc[7].x, a0); a1 = fmaf(q1.w, kvc[7].y, a1);
            a2 = fmaf(q1.w, kvc[7].z, a2); a3 = fmaf(q1.w, kvc[7].w, a3);
            acc[r][0] = a0; acc[r][1] = a1; acc[r][2] = a2; acc[r][3] = a3;
        }
    }

#pragma unroll
    for (int r = 0; r < 8; ++r) {
        const float z = 1.f / (dot[r] + 1e-6f);
        // lanes 0..63 cover float4 0..63 of the row -> 1KB dense store
        og[(size_t)(r0 + r) * 64 + lane] =
            make_float4(acc[r][0] * z, acc[r][1] * z, acc[r][2] * z, acc[r][3] * z);
    }
}

extern "C" void kernel_launch(void* const* d_in, const int* in_sizes, int n_in,
                              void* d_out, int out_size, void* d_ws, size_t ws_size,
                              hipStream_t stream)
{
    const float* queries = (const float*)d_in[0];
    const float* keys    = (const float*)d_in[1];
    const float* values  = (const float*)d_in[2];
    float* out = (float*)d_out;
    float* ws  = (float*)d_ws;

    const size_t partial_elems = (size_t)NH_ * CHUNKS_ * PKS_; // 2,162,688 floats
    const size_t final_elems   = (size_t)NH_ * PKS_;           // 67,584 floats
    const dim3 blk(256);
    const int p2_blocks = (N_ * L_) / RPB_;                    // 2048

    if (ws_size >= (partial_elems + final_elems) * sizeof(float)) {
        // deterministic two-stage reduction
        float* partials = ws;
        float* kvf      = ws + partial_elems;
        la_phase1<false><<<dim3(NH_, CHUNKS_), blk, 0, stream>>>(keys, values, partials);
        la_reduce<<<dim3(NH_), blk, 0, stream>>>(partials, kvf);
        la_phase2<<<dim3(p2_blocks), blk, 0, stream>>>(queries, kvf, out);
    } else {
        // fallback: atomic accumulation into zeroed final buffer
        float* kvf = ws;
        const int nz = (int)final_elems;
        la_zero<<<dim3((nz + 255) / 256), blk, 0, stream>>>(kvf, nz);
        la_phase1<true><<<dim3(NH_, CHUNKS_), blk, 0, stream>>>(keys, values, kvf);
        la_phase2<<<dim3(p2_blocks), blk, 0, stream>>>(queries, kvf, out);
    }
}